// Round 19
// baseline (123.320 us; speedup 1.0000x reference)
//
#include <hip/hip_runtime.h>
#include <cmath>

namespace {
constexpr int NB = 16384;
constexpr int NS = 50;
constexpr int NK = 5;
constexpr int NH = 32;

// sharded f64 stat layout (8 shards x 312 doubles) + loss + counter
constexpr int AU_SUM = 0, AU_SQ = 36, D1_SUM = 72, D1_SQ = 152, D2_SUM = 232, D2_SQ = 272;
constexpr int SHARD_STRIDE = 312;
constexpr int NSHARD = 8;
constexpr int LOSS_OFF = SHARD_STRIDE * NSHARD;      // 2496
constexpr int CNT_OFF  = LOSS_OFF + 1;               // 2497 (as int storage)

typedef __attribute__((ext_vector_type(8))) short bf16x8;
typedef __attribute__((ext_vector_type(4))) float f32x4;

__device__ __forceinline__ float wsum64(float v) {
#pragma unroll
  for (int off = 32; off; off >>= 1) v += __shfl_xor(v, off, 64);
  return v;
}

__device__ __forceinline__ float sigm(float x) { return 1.0f / (1.0f + expf(-x)); }

__device__ __forceinline__ unsigned short f2bf(float f) {
  union { float f; unsigned u; } v; v.f = f;
  unsigned r = v.u + 0x7fffu + ((v.u >> 16) & 1u);
  return (unsigned short)(r >> 16);
}

__device__ __forceinline__ float bf2f(unsigned short b) {
  union { unsigned u; float f; } v; v.u = ((unsigned)b) << 16;
  return v.f;
}

// ---- prep: bf16 copy of au_W1 (k1 B-operand), [48][144] ---------------------
__global__ __launch_bounds__(512) void w1prep(const float* __restrict__ au_W1,
                                              unsigned short* __restrict__ ws_w1t) {
  for (int e = threadIdx.x; e < 48 * 144; e += 512) {
    const int n = e / 144, k = e - 144 * n;
    float v = 0.f;
    if (n < 36 && k < 128) {
      const int i = (k < 64) ? k : (k + 1);
      v = au_W1[i * 36 + n];
    }
    ws_w1t[e] = f2bf(v);
  }
}

// ---- Kernel 1: embeddings, sim, top-5, x @ au_W1 via MFMA, au-BN stats ------
// 256 thr = 4 waves; 8 rows/block (grid 2048), 2 serial rows/wave.
// Frozen per-lane sim/top-k FP block: textually identical to R18.
// GEMM B-operand from global bf16 ws_w1t (no per-block W1 staging).
__global__ __launch_bounds__(256) void k1(
    const int* __restrict__ iid, const int* __restrict__ aid,
    const int* __restrict__ hist_iid, const int* __restrict__ hist_aid,
    const int* __restrict__ hist_rate,
    const float* __restrict__ item_tab, const float* __restrict__ cate_tab,
    const float* __restrict__ au_W1, const float* __restrict__ au_b1,
    const float* __restrict__ l1_W, const float* __restrict__ l2_W,
    const unsigned short* __restrict__ ws_w1t,
    float* __restrict__ ws_y,
    unsigned short* __restrict__ ws_xw, unsigned short* __restrict__ ws_ic,
    int* __restrict__ ws_hr,
    unsigned short* __restrict__ ws_l1t, unsigned short* __restrict__ ws_l2t,
    double* __restrict__ gstats)
{
  const int tid = threadIdx.x;
  const int lane = tid & 63;
  const int wv = tid >> 6;
  const int shard = blockIdx.x & (NSHARD - 1);

  __shared__ alignas(16) unsigned short xb[48][136];
  __shared__ float icsh[4][64];
  __shared__ float crossm[40];
  __shared__ float w1c[36], b1s[36];
  __shared__ float psum[36], psq[36];

  // zero pad rows 40..47 of xb
  for (int e = tid; e < 8 * 136; e += 256) {
    xb[40 + e / 136][e - 136 * (e / 136)] = 0;
  }
  if (tid < 36) {
    w1c[tid] = au_W1[64 * 36 + tid];
    b1s[tid] = au_b1[tid];
    psum[tid] = 0.f; psq[tid] = 0.f;
  }

  for (int r = 0; r < 2; r++) {
    const int lm = r * 4 + wv;
    const int row = blockIdx.x * 8 + lm;

    const int iv = iid[row];
    const int cv = aid[row];
    const float ic = (lane < 32) ? item_tab[iv * NH + lane] : cate_tab[cv * NH + lane - 32];
    icsh[wv][lane] = ic;
    const float n1 = sqrtf(wsum64(ic * ic));

    int hi = 0, ha = 0, rv = 0;
    float dotv = 0.f, sim = -INFINITY;
    if (lane < NS) {
      hi = hist_iid[row * NS + lane];
      ha = hist_aid[row * NS + lane];
      rv = hist_rate[row * NS + lane];
      const float4* ip = reinterpret_cast<const float4*>(item_tab + (size_t)hi * NH);
      const float4* cp = reinterpret_cast<const float4*>(cate_tab + (size_t)ha * NH);
      const float* ics = icsh[wv];
      float n2sq = 0.f;
#pragma unroll
      for (int q = 0; q < 8; q++) {
        float4 a = ip[q];
        dotv += ics[4*q+0]*a.x + ics[4*q+1]*a.y + ics[4*q+2]*a.z + ics[4*q+3]*a.w;
        n2sq += a.x*a.x + a.y*a.y + a.z*a.z + a.w*a.w;
      }
#pragma unroll
      for (int q = 0; q < 8; q++) {
        float4 a = cp[q];
        dotv += ics[32+4*q+0]*a.x + ics[32+4*q+1]*a.y + ics[32+4*q+2]*a.z + ics[32+4*q+3]*a.w;
        n2sq += a.x*a.x + a.y*a.y + a.z*a.z + a.w*a.w;
      }
      sim = dotv / fmaxf(n1 * sqrtf(n2sq), 1e-8f);
    }

    // rank-based top-5: desc value, asc index (== jax.lax.top_k)
    int rank = 0;
#pragma unroll
    for (int j = 0; j < NS; j++) {
      const float sj = __shfl(sim, j, 64);
      rank += (sj > sim) || (sj == sim && j < lane);
    }
    int tk[NK]; float vals[NK];
#pragma unroll
    for (int k = 0; k < NK; k++) {
      const unsigned long long mk = __ballot((lane < NS) && (rank == k));
      tk[k] = __ffsll((long long)mk) - 1;
    }
#pragma unroll
    for (int k = 0; k < NK; k++) vals[k] = __shfl(sim, tk[k], 64);

    const float ssumw = vals[0] + vals[1] + vals[2] + vals[3] + vals[4] + 1e-8f;
    const unsigned short icb = f2bf(ic);
    ws_ic[(size_t)row * 64 + lane] = icb;
#pragma unroll
    for (int k = 0; k < NK; k++) {
      const float wk = vals[k] / ssumw;
      const float crossk = wk * __shfl(dotv, tk[k], 64);
      const int hik = __shfl(hi, tk[k], 64);
      const int hak = __shfl(ha, tk[k], 64);
      const int rvk = __shfl(rv, tk[k], 64);
      const float e = (lane < 32) ? item_tab[hik * NH + lane] : cate_tab[hak * NH + lane - 32];
      const int m = lm * 5 + k;
      const unsigned short xwb = f2bf(wk * e);
      xb[m][lane] = xwb;
      xb[m][64 + lane] = icb;
      ws_xw[((size_t)row * NK + k) * 64 + lane] = xwb;
      if (lane == 0) crossm[m] = crossk;
      if (lane == k) ws_hr[row * NK + k] = rvk;
    }
  }
  __syncthreads();

  // MFMA GEMM: M=40->48 (3 tiles), N=36->48 (3 tiles), K=128 (4 steps);
  // B from global bf16 ws_w1t [48][144] (L1/L2-hot, shared by all blocks).
  const int l15 = lane & 15, lhi = lane >> 4;
  for (int t = wv; t < 9; t += 4) {
    const int mt = t / 3, nt = t - 3 * mt;
    f32x4 acc = {0.f, 0.f, 0.f, 0.f};
#pragma unroll
    for (int ks = 0; ks < 4; ks++) {
      const int k0 = ks * 32 + lhi * 8;
      const bf16x8 a = *reinterpret_cast<const bf16x8*>(&xb[mt * 16 + l15][k0]);
      const bf16x8 b = *reinterpret_cast<const bf16x8*>(
          &ws_w1t[(size_t)(nt * 16 + l15) * 144 + k0]);
      acc = __builtin_amdgcn_mfma_f32_16x16x32_bf16(a, b, acc, 0, 0, 0);
    }
    const int n = nt * 16 + l15;
    if (n < 36) {
      const float w1cn = w1c[n], b1n = b1s[n];
      float ls = 0.f, lq = 0.f;
      bool any = false;
#pragma unroll
      for (int reg = 0; reg < 4; reg++) {
        const int m = mt * 16 + 4 * lhi + reg;
        if (m < 40) {
          const float y = acc[reg] + b1n + crossm[m] * w1cn;
          ws_y[(size_t)(blockIdx.x * 40 + m) * 36 + n] = y;
          ls += y; lq += y * y;
          any = true;
        }
      }
      if (any) {
        atomicAdd(&psum[n], ls);
        atomicAdd(&psq[n], lq);
      }
    }
  }
  __syncthreads();
  if (tid < 36) {
    atomicAdd(&gstats[shard * SHARD_STRIDE + AU_SUM + tid], (double)psum[tid]);
    atomicAdd(&gstats[shard * SHARD_STRIDE + AU_SQ + tid], (double)psq[tid]);
  }

  // folded weight prep (consumers k3/k5 launch after k1 completes)
  if (blockIdx.x == 0) {
    for (int e = tid; e < 80 * 168; e += 256) {
      const int n = e / 168, k = e - 168 * n;
      ws_l1t[e] = (k < 160) ? f2bf(l1_W[k * 80 + n]) : (unsigned short)0;
    }
  } else if (blockIdx.x == 1) {
    for (int e = tid; e < 48 * 104; e += 256) {
      const int n = e / 104, k = e - 104 * n;
      ws_l2t[e] = (n < 40 && k < 80) ? f2bf(l2_W[k * 40 + n]) : (unsigned short)0;
    }
  }
}

// ---- Kernel 3: dice3 (LDS-staged aout), final_hist, res @ l1_W, d1 stats ----
// 16 rows/block (grid 1024). B-operand from global bf16. (R18-verbatim)
__global__ __launch_bounds__(512) void k3(
    const float* __restrict__ rate_tab,
    const float* __restrict__ au_alpha, const float* __restrict__ au_beta,
    const float* __restrict__ au_gamma, const float* __restrict__ au_bbeta,
    const float* __restrict__ au_W2, const float* __restrict__ au_b2,
    const unsigned short* __restrict__ ws_l1t, const float* __restrict__ l1_b,
    const float* __restrict__ ws_y,
    const unsigned short* __restrict__ ws_xw, const unsigned short* __restrict__ ws_ic,
    const int* __restrict__ ws_hr,
    double* __restrict__ gstats,
    float* __restrict__ ws_h1)
{
  const int tid = threadIdx.x, lane = tid & 63, wv = tid >> 6;
  const int base = blockIdx.x * 16;
  const int shard = blockIdx.x & (NSHARD - 1);
  __shared__ alignas(16) unsigned short resb[16][168];
  __shared__ float ysh[80][37];
  __shared__ float aoutsh[80];
  __shared__ float asc[36], bsc[36], bets[36], alps[36], w2s[36];
  __shared__ float psum[80], psq[80];

  for (int e = tid; e < 80 * 36; e += 512) {
    ysh[e / 36][e % 36] = ws_y[(size_t)base * 180 + e];
  }
  if (tid < 36) {
    double s = 0.0, q = 0.0;
#pragma unroll
    for (int sh = 0; sh < NSHARD; sh++) {
      s += gstats[sh * SHARD_STRIDE + AU_SUM + tid];
      q += gstats[sh * SHARD_STRIDE + AU_SQ + tid];
    }
    const double m = s * (1.0 / ((double)NB * NK));
    const double var = q * (1.0 / ((double)NB * NK)) - m * m;
    const float rstd = (float)(1.0 / sqrt(var + 1e-8));
    const float g = au_gamma[tid] * rstd;
    asc[tid] = g; bsc[tid] = au_bbeta[tid] - (float)m * g;
    bets[tid] = au_beta[tid];
    alps[tid] = au_alpha[tid];
    w2s[tid] = au_W2[tid];
  }
  if (tid < 80) { psum[tid] = 0.f; psq[tid] = 0.f; }
  __syncthreads();

  const float bias2 = au_b2[0];
  if (tid < 80) {
    float acc = 0.f;
#pragma unroll
    for (int j = 0; j < 36; j++) {
      const float yv = ysh[tid][j];
      const float bn = yv * asc[j] + bsc[j];
      const float xn = sigm(bets[j] * bn);
      acc = fmaf(alps[j] * (1.f - xn) * yv + xn * yv, w2s[j], acc);
    }
    aoutsh[tid] = acc + bias2;
  }
  __syncthreads();

  for (int r = 0; r < 2; r++) {
    const int lm = r * 8 + wv;
    const int row = base + lm;
    const unsigned short icb = ws_ic[(size_t)row * 64 + lane];
    float fh0 = 0.f, fh1 = 0.f;
#pragma unroll
    for (int k = 0; k < NK; k++) {
      const float aok = aoutsh[lm * 5 + k];
      const unsigned short xwb = ws_xw[((size_t)row * NK + k) * 64 + lane];
      fh0 = fmaf(bf2f(xwb), aok, fh0);
      if (lane < 32) {
        const int rvk = ws_hr[row * NK + k];
        fh1 = fmaf(rate_tab[rvk * NH + lane], aok, fh1);
      }
    }
    resb[lm][lane] = icb;
    resb[lm][64 + lane] = f2bf(fh0);
    if (lane < 32) resb[lm][128 + lane] = f2bf(fh1);
  }
  __syncthreads();

  // GEMM M=16 (1 tile) x N=80 (5 nt), K=160 (5 steps); waves 0-4
  const int l15 = lane & 15, lhi = lane >> 4;
  if (wv < 5) {
    const int nt = wv;
    f32x4 acc = {0.f, 0.f, 0.f, 0.f};
#pragma unroll
    for (int ks = 0; ks < 5; ks++) {
      const int k0 = ks * 32 + lhi * 8;
      const bf16x8 a = *reinterpret_cast<const bf16x8*>(&resb[l15][k0]);
      const bf16x8 b = *reinterpret_cast<const bf16x8*>(
          &ws_l1t[(size_t)(nt * 16 + l15) * 168 + k0]);
      acc = __builtin_amdgcn_mfma_f32_16x16x32_bf16(a, b, acc, 0, 0, 0);
    }
    const int n = nt * 16 + l15;
    const float bn = l1_b[n];
    float ls = 0.f, lq = 0.f;
#pragma unroll
    for (int reg = 0; reg < 4; reg++) {
      const int m = 4 * lhi + reg;
      const float h = acc[reg] + bn;
      ws_h1[(size_t)(base + m) * 80 + n] = h;
      ls += h; lq += h * h;
    }
    atomicAdd(&psum[n], ls);
    atomicAdd(&psq[n], lq);
  }
  __syncthreads();
  if (tid < 80) {
    atomicAdd(&gstats[shard * SHARD_STRIDE + D1_SUM + tid], (double)psum[tid]);
    atomicAdd(&gstats[shard * SHARD_STRIDE + D1_SQ + tid], (double)psq[tid]);
  }
}

// ---- Kernel 5: dice2(h1), h @ l2_W via MFMA, d2 stats (16 rows/block) -------
__global__ __launch_bounds__(512) void k5(
    const float* __restrict__ d1_alpha, const float* __restrict__ d1_beta,
    const float* __restrict__ d1_gamma, const float* __restrict__ d1_bbeta,
    const unsigned short* __restrict__ ws_l2t, const float* __restrict__ l2_b,
    const float* __restrict__ ws_h1,
    double* __restrict__ gstats,
    float* __restrict__ ws_h2)
{
  const int tid = threadIdx.x, lane = tid & 63, wv = tid >> 6;
  const int shard = blockIdx.x & (NSHARD - 1);
  __shared__ alignas(16) unsigned short h1b[16][104];
  __shared__ float a1[80], c1[80];
  __shared__ float psum[40], psq[40];

  if (tid < 80) {
    double s = 0.0, q = 0.0;
#pragma unroll
    for (int sh = 0; sh < NSHARD; sh++) {
      s += gstats[sh * SHARD_STRIDE + D1_SUM + tid];
      q += gstats[sh * SHARD_STRIDE + D1_SQ + tid];
    }
    const double m = s * (1.0 / (double)NB);
    const double var = q * (1.0 / (double)NB) - m * m;
    const float rstd = (float)(1.0 / sqrt(var + 1e-8));
    const float g = d1_gamma[tid] * rstd;
    a1[tid] = g; c1[tid] = d1_bbeta[tid] - (float)m * g;
  }
  if (tid < 40) { psum[tid] = 0.f; psq[tid] = 0.f; }
  __syncthreads();

  for (int r = 0; r < 2; r++) {
    const int lm = r * 8 + wv;
    const int row = blockIdx.x * 16 + lm;
    {
      const float v = ws_h1[(size_t)row * 80 + lane];
      const float bn = v * a1[lane] + c1[lane];
      const float xn = sigm(d1_beta[lane] * bn);
      h1b[lm][lane] = f2bf(d1_alpha[lane] * (1.f - xn) * v + xn * v);
    }
    const int o = 64 + lane;
    if (lane < 16) {
      const float v = ws_h1[(size_t)row * 80 + o];
      const float bn = v * a1[o] + c1[o];
      const float xn = sigm(d1_beta[o] * bn);
      h1b[lm][o] = f2bf(d1_alpha[o] * (1.f - xn) * v + xn * v);
    } else if (lane < 32) {
      h1b[lm][o] = 0;
    }
  }
  __syncthreads();

  // GEMM M=16 (1 tile) x N=48 (3 nt), K=96 (3 steps); waves 0-2
  const int l15 = lane & 15, lhi = lane >> 4;
  if (wv < 3) {
    const int nt = wv;
    f32x4 acc = {0.f, 0.f, 0.f, 0.f};
#pragma unroll
    for (int ks = 0; ks < 3; ks++) {
      const int k0 = ks * 32 + lhi * 8;
      const bf16x8 a = *reinterpret_cast<const bf16x8*>(&h1b[l15][k0]);
      const bf16x8 b = *reinterpret_cast<const bf16x8*>(
          &ws_l2t[(size_t)(nt * 16 + l15) * 104 + k0]);
      acc = __builtin_amdgcn_mfma_f32_16x16x32_bf16(a, b, acc, 0, 0, 0);
    }
    const int n = nt * 16 + l15;
    if (n < 40) {
      const float bn = l2_b[n];
      float ls = 0.f, lq = 0.f;
#pragma unroll
      for (int reg = 0; reg < 4; reg++) {
        const int m = 4 * lhi + reg;
        const float h = acc[reg] + bn;
        ws_h2[(size_t)(blockIdx.x * 16 + m) * 40 + n] = h;
        ls += h; lq += h * h;
      }
      atomicAdd(&psum[n], ls);
      atomicAdd(&psq[n], lq);
    }
  }
  __syncthreads();
  if (tid < 40) {
    atomicAdd(&gstats[shard * SHARD_STRIDE + D2_SUM + tid], (double)psum[tid]);
    atomicAdd(&gstats[shard * SHARD_STRIDE + D2_SQ + tid], (double)psq[tid]);
  }
}

// ---- Kernel 7: dice2(h2), logits, probs, loss (+ last-block finalize) -------
// 512 thr, 32 rows/block (grid 512).
__global__ __launch_bounds__(512) void k7(
    const int* __restrict__ lb,
    const float* __restrict__ d2_alpha, const float* __restrict__ d2_beta,
    const float* __restrict__ d2_gamma, const float* __restrict__ d2_bbeta,
    const float* __restrict__ l3_W, const float* __restrict__ l3_b,
    const float* __restrict__ ws_h2,
    double* __restrict__ gstats,
    float* __restrict__ out)
{
  const int tid = threadIdx.x, lane = tid & 63, wv = tid >> 6;
  __shared__ float a2[40], c2[40];
  __shared__ float wls[8];
  if (tid < 40) {
    double s = 0.0, q = 0.0;
#pragma unroll
    for (int sh = 0; sh < NSHARD; sh++) {
      s += gstats[sh * SHARD_STRIDE + D2_SUM + tid];
      q += gstats[sh * SHARD_STRIDE + D2_SQ + tid];
    }
    const double m = s * (1.0 / (double)NB);
    const double var = q * (1.0 / (double)NB) - m * m;
    const float rstd = (float)(1.0 / sqrt(var + 1e-8));
    const float g = d2_gamma[tid] * rstd;
    a2[tid] = g; c2[tid] = d2_bbeta[tid] - (float)m * g;
  }
  __syncthreads();

  float wj = 0, b2j = 0, c2j = 0, betaj = 0, alphaj = 0;
  if (lane < 40) {
    wj = l3_W[lane]; b2j = a2[lane]; c2j = c2[lane];
    betaj = d2_beta[lane]; alphaj = d2_alpha[lane];
  }
  const float b3 = l3_b[0];

  float lacc = 0.f;
  for (int r = 0; r < 4; r++) {
    const int row = blockIdx.x * 32 + r * 8 + wv;
    float p = 0.f;
    if (lane < 40) {
      const float v = ws_h2[(size_t)row * 40 + lane];
      const float bn = v * b2j + c2j;
      const float xn = sigm(betaj * bn);
      p = (alphaj * (1.f - xn) * v + xn * v) * wj;
    }
    const float logit = wsum64(p) + b3;
    if (lane == 0) {
      out[row] = 1.f / (1.f + expf(-logit));
      const float lab = (float)lb[row];
      lacc += fmaxf(logit, 0.f) - logit * lab + log1pf(expf(-fabsf(logit)));
    }
  }
  if (lane == 0) wls[wv] = lacc;
  __syncthreads();
  if (tid == 0) {
    double* g_loss = gstats + LOSS_OFF;
    unsigned int* g_cnt = (unsigned int*)(gstats + CNT_OFF);
    float s = 0.f;
#pragma unroll
    for (int w = 0; w < 8; w++) s += wls[w];
    atomicAdd(g_loss, (double)s);
    __threadfence();
    const unsigned prev = atomicAdd(g_cnt, 1u);
    if (prev == (unsigned)(gridDim.x - 1)) {
      const double tot = atomicAdd(g_loss, 0.0);
      out[NB] = (float)(tot * (1.0 / (double)NB));
    }
  }
}

} // namespace

extern "C" void kernel_launch(void* const* d_in, const int* in_sizes, int n_in,
                              void* d_out, int out_size, void* d_ws, size_t ws_size,
                              hipStream_t stream) {
  const int* iid       = (const int*)d_in[0];
  const int* aid       = (const int*)d_in[1];
  const int* lb        = (const int*)d_in[2];
  const int* hist_iid  = (const int*)d_in[3];
  const int* hist_aid  = (const int*)d_in[4];
  const int* hist_rate = (const int*)d_in[5];
  const float* item_tab = (const float*)d_in[6];
  const float* cate_tab = (const float*)d_in[7];
  const float* rate_tab = (const float*)d_in[8];
  const float* au_W1    = (const float*)d_in[9];
  const float* au_b1    = (const float*)d_in[10];
  const float* au_alpha = (const float*)d_in[11];
  const float* au_beta  = (const float*)d_in[12];
  const float* au_gamma = (const float*)d_in[13];
  const float* au_bbeta = (const float*)d_in[14];
  const float* au_W2    = (const float*)d_in[15];
  const float* au_b2    = (const float*)d_in[16];
  const float* l1_W     = (const float*)d_in[17];
  const float* l1_b     = (const float*)d_in[18];
  const float* d1_alpha = (const float*)d_in[19];
  const float* d1_beta  = (const float*)d_in[20];
  const float* d1_gamma = (const float*)d_in[21];
  const float* d1_bbeta = (const float*)d_in[22];
  const float* l2_W     = (const float*)d_in[23];
  const float* l2_b     = (const float*)d_in[24];
  const float* d2_alpha = (const float*)d_in[25];
  const float* d2_beta  = (const float*)d_in[26];
  const float* d2_gamma = (const float*)d_in[27];
  const float* d2_bbeta = (const float*)d_in[28];
  const float* l3_W     = (const float*)d_in[29];
  const float* l3_b     = (const float*)d_in[30];
  float* out = (float*)d_out;

  double* gstats = (double*)d_ws;
  float* fbase  = (float*)((char*)d_ws + 32768);
  float* ws_y   = fbase;                                  // NB*180 f32
  float* ws_h1  = fbase + (size_t)NB * 180;               // NB*80 f32
  float* ws_h2  = ws_h1 + (size_t)NB * 80;                // NB*40 f32
  int*   ws_hr  = (int*)(ws_h2 + (size_t)NB * 40);        // NB*5 int
  unsigned short* ws_xw = (unsigned short*)(ws_hr + (size_t)NB * NK); // NB*5*64 bf16
  unsigned short* ws_ic = ws_xw + (size_t)NB * NK * 64;   // NB*64 bf16
  unsigned short* ws_l1t = ws_ic + (size_t)NB * 64;       // 80*168 bf16
  unsigned short* ws_l2t = ws_l1t + 80 * 168;             // 48*104 bf16
  unsigned short* ws_w1t = ws_l2t + 48 * 104;             // 48*144 bf16

  hipMemsetAsync(d_ws, 0, (CNT_OFF + 2) * sizeof(double), stream);
  w1prep<<<dim3(1), 512, 0, stream>>>(au_W1, ws_w1t);
  k1<<<dim3(NB / 8), 256, 0, stream>>>(iid, aid, hist_iid, hist_aid, hist_rate,
                              item_tab, cate_tab, au_W1, au_b1, l1_W, l2_W, ws_w1t,
                              ws_y, ws_xw, ws_ic, ws_hr, ws_l1t, ws_l2t, gstats);
  k3<<<dim3(NB / 16), 512, 0, stream>>>(rate_tab,
                              au_alpha, au_beta, au_gamma, au_bbeta, au_W2, au_b2,
                              ws_l1t, l1_b, ws_y, ws_xw, ws_ic, ws_hr,
                              gstats, ws_h1);
  k5<<<dim3(NB / 16), 512, 0, stream>>>(d1_alpha, d1_beta, d1_gamma, d1_bbeta,
                              ws_l2t, l2_b, ws_h1, gstats, ws_h2);
  k7<<<dim3(NB / 32), 512, 0, stream>>>(lb, d2_alpha, d2_beta, d2_gamma, d2_bbeta, l3_W, l3_b,
                              ws_h2, gstats, out);
}

// Round 20
// 119.604 us; speedup vs baseline: 1.0311x; 1.0311x over previous
//
#include <hip/hip_runtime.h>
#include <cmath>

namespace {
constexpr int NB = 16384;
constexpr int NS = 50;
constexpr int NK = 5;
constexpr int NH = 32;

// sharded f64 stat layout (8 shards x 312 doubles) + loss + counter
constexpr int AU_SUM = 0, AU_SQ = 36, D1_SUM = 72, D1_SQ = 152, D2_SUM = 232, D2_SQ = 272;
constexpr int SHARD_STRIDE = 312;
constexpr int NSHARD = 8;
constexpr int LOSS_OFF = SHARD_STRIDE * NSHARD;      // 2496
constexpr int CNT_OFF  = LOSS_OFF + 1;               // 2497 (as int storage)

typedef __attribute__((ext_vector_type(8))) short bf16x8;
typedef __attribute__((ext_vector_type(4))) float f32x4;

__device__ __forceinline__ float wsum64(float v) {
#pragma unroll
  for (int off = 32; off; off >>= 1) v += __shfl_xor(v, off, 64);
  return v;
}

__device__ __forceinline__ float sigm(float x) { return 1.0f / (1.0f + expf(-x)); }

__device__ __forceinline__ unsigned short f2bf(float f) {
  union { float f; unsigned u; } v; v.f = f;
  unsigned r = v.u + 0x7fffu + ((v.u >> 16) & 1u);
  return (unsigned short)(r >> 16);
}

__device__ __forceinline__ float bf2f(unsigned short b) {
  union { unsigned u; float f; } v; v.u = ((unsigned)b) << 16;
  return v.f;
}

// ---- Kernel 1: embeddings, sim, top-5, x @ au_W1 via MFMA, au-BN stats ------
// R18-verbatim (best measured). Sim arithmetic frozen (-ffp-contract depends
// on code shape; restructuring flips top-k selection on marginal rows).
__global__ __launch_bounds__(512) void k1(
    const int* __restrict__ iid, const int* __restrict__ aid,
    const int* __restrict__ hist_iid, const int* __restrict__ hist_aid,
    const int* __restrict__ hist_rate,
    const float* __restrict__ item_tab, const float* __restrict__ cate_tab,
    const float* __restrict__ au_W1, const float* __restrict__ au_b1,
    const float* __restrict__ l1_W, const float* __restrict__ l2_W,
    float* __restrict__ ws_y,
    unsigned short* __restrict__ ws_xw, unsigned short* __restrict__ ws_ic,
    int* __restrict__ ws_hr,
    unsigned short* __restrict__ ws_l1t, unsigned short* __restrict__ ws_l2t,
    double* __restrict__ gstats)
{
  const int tid = threadIdx.x;
  const int lane = tid & 63;
  const int wv = tid >> 6;
  const int shard = blockIdx.x & (NSHARD - 1);

  __shared__ alignas(16) unsigned short w1t[48][136];
  __shared__ alignas(16) unsigned short xb[80][136];
  __shared__ float icsh[8][64];
  __shared__ float crossm[80];
  __shared__ float w1c[36], b1s[36];
  __shared__ float psum[36], psq[36];

  for (int e = tid; e < 48 * 136; e += 512) {
    const int n = e / 136, k = e - 136 * n;
    float v = 0.f;
    if (n < 36 && k < 128) {
      const int i = (k < 64) ? k : (k + 1);
      v = au_W1[i * 36 + n];
    }
    w1t[n][k] = f2bf(v);
  }
  if (tid < 36) {
    w1c[tid] = au_W1[64 * 36 + tid];
    b1s[tid] = au_b1[tid];
    psum[tid] = 0.f; psq[tid] = 0.f;
  }

  for (int r = 0; r < 2; r++) {
    const int lm = r * 8 + wv;
    const int row = blockIdx.x * 16 + lm;

    const int iv = iid[row];
    const int cv = aid[row];
    const float ic = (lane < 32) ? item_tab[iv * NH + lane] : cate_tab[cv * NH + lane - 32];
    icsh[wv][lane] = ic;
    const float n1 = sqrtf(wsum64(ic * ic));

    int hi = 0, ha = 0, rv = 0;
    float dotv = 0.f, sim = -INFINITY;
    if (lane < NS) {
      hi = hist_iid[row * NS + lane];
      ha = hist_aid[row * NS + lane];
      rv = hist_rate[row * NS + lane];
      const float4* ip = reinterpret_cast<const float4*>(item_tab + (size_t)hi * NH);
      const float4* cp = reinterpret_cast<const float4*>(cate_tab + (size_t)ha * NH);
      const float* ics = icsh[wv];
      float n2sq = 0.f;
#pragma unroll
      for (int q = 0; q < 8; q++) {
        float4 a = ip[q];
        dotv += ics[4*q+0]*a.x + ics[4*q+1]*a.y + ics[4*q+2]*a.z + ics[4*q+3]*a.w;
        n2sq += a.x*a.x + a.y*a.y + a.z*a.z + a.w*a.w;
      }
#pragma unroll
      for (int q = 0; q < 8; q++) {
        float4 a = cp[q];
        dotv += ics[32+4*q+0]*a.x + ics[32+4*q+1]*a.y + ics[32+4*q+2]*a.z + ics[32+4*q+3]*a.w;
        n2sq += a.x*a.x + a.y*a.y + a.z*a.z + a.w*a.w;
      }
      sim = dotv / fmaxf(n1 * sqrtf(n2sq), 1e-8f);
    }

    // rank-based top-5: desc value, asc index (== jax.lax.top_k)
    int rank = 0;
#pragma unroll
    for (int j = 0; j < NS; j++) {
      const float sj = __shfl(sim, j, 64);
      rank += (sj > sim) || (sj == sim && j < lane);
    }
    int tk[NK]; float vals[NK];
#pragma unroll
    for (int k = 0; k < NK; k++) {
      const unsigned long long mk = __ballot((lane < NS) && (rank == k));
      tk[k] = __ffsll((long long)mk) - 1;
    }
#pragma unroll
    for (int k = 0; k < NK; k++) vals[k] = __shfl(sim, tk[k], 64);

    const float ssumw = vals[0] + vals[1] + vals[2] + vals[3] + vals[4] + 1e-8f;
    const unsigned short icb = f2bf(ic);
    ws_ic[(size_t)row * 64 + lane] = icb;
#pragma unroll
    for (int k = 0; k < NK; k++) {
      const float wk = vals[k] / ssumw;
      const float crossk = wk * __shfl(dotv, tk[k], 64);
      const int hik = __shfl(hi, tk[k], 64);
      const int hak = __shfl(ha, tk[k], 64);
      const int rvk = __shfl(rv, tk[k], 64);
      const float e = (lane < 32) ? item_tab[hik * NH + lane] : cate_tab[hak * NH + lane - 32];
      const int m = lm * 5 + k;
      const unsigned short xwb = f2bf(wk * e);
      xb[m][lane] = xwb;
      xb[m][64 + lane] = icb;
      ws_xw[((size_t)row * NK + k) * 64 + lane] = xwb;
      if (lane == 0) crossm[m] = crossk;
      if (lane == k) ws_hr[row * NK + k] = rvk;
    }
  }
  __syncthreads();

  // MFMA GEMM: M=80 (5 tiles), N=36->48 (3 tiles), K=128 (4 steps)
  const int l15 = lane & 15, lhi = lane >> 4;
  for (int t = wv; t < 15; t += 8) {
    const int mt = t / 3, nt = t - 3 * mt;
    f32x4 acc = {0.f, 0.f, 0.f, 0.f};
#pragma unroll
    for (int ks = 0; ks < 4; ks++) {
      const int k0 = ks * 32 + lhi * 8;
      const bf16x8 a = *reinterpret_cast<const bf16x8*>(&xb[mt * 16 + l15][k0]);
      const bf16x8 b = *reinterpret_cast<const bf16x8*>(&w1t[nt * 16 + l15][k0]);
      acc = __builtin_amdgcn_mfma_f32_16x16x32_bf16(a, b, acc, 0, 0, 0);
    }
    const int n = nt * 16 + l15;
    if (n < 36) {
      const float w1cn = w1c[n], b1n = b1s[n];
      float ls = 0.f, lq = 0.f;
#pragma unroll
      for (int reg = 0; reg < 4; reg++) {
        const int m = mt * 16 + 4 * lhi + reg;
        const float y = acc[reg] + b1n + crossm[m] * w1cn;
        ws_y[(size_t)(blockIdx.x * 80 + m) * 36 + n] = y;
        ls += y; lq += y * y;
      }
      atomicAdd(&psum[n], ls);
      atomicAdd(&psq[n], lq);
    }
  }
  __syncthreads();
  if (tid < 36) {
    atomicAdd(&gstats[shard * SHARD_STRIDE + AU_SUM + tid], (double)psum[tid]);
    atomicAdd(&gstats[shard * SHARD_STRIDE + AU_SQ + tid], (double)psq[tid]);
  }

  // folded weight prep (consumers k3/k5 launch after k1 completes)
  if (blockIdx.x == 0) {
    for (int e = tid; e < 80 * 168; e += 512) {
      const int n = e / 168, k = e - 168 * n;
      ws_l1t[e] = (k < 160) ? f2bf(l1_W[k * 80 + n]) : (unsigned short)0;
    }
  } else if (blockIdx.x == 1) {
    for (int e = tid; e < 48 * 104; e += 512) {
      const int n = e / 104, k = e - 104 * n;
      ws_l2t[e] = (n < 40 && k < 80) ? f2bf(l2_W[k * 40 + n]) : (unsigned short)0;
    }
  }
}

// ---- Kernel 3: dice3 (LDS-staged aout), final_hist, res @ l1_W, d1 stats ----
// 16 rows/block (grid 1024). B-operand from global bf16.
__global__ __launch_bounds__(512) void k3(
    const float* __restrict__ rate_tab,
    const float* __restrict__ au_alpha, const float* __restrict__ au_beta,
    const float* __restrict__ au_gamma, const float* __restrict__ au_bbeta,
    const float* __restrict__ au_W2, const float* __restrict__ au_b2,
    const unsigned short* __restrict__ ws_l1t, const float* __restrict__ l1_b,
    const float* __restrict__ ws_y,
    const unsigned short* __restrict__ ws_xw, const unsigned short* __restrict__ ws_ic,
    const int* __restrict__ ws_hr,
    double* __restrict__ gstats,
    float* __restrict__ ws_h1)
{
  const int tid = threadIdx.x, lane = tid & 63, wv = tid >> 6;
  const int base = blockIdx.x * 16;
  const int shard = blockIdx.x & (NSHARD - 1);
  __shared__ alignas(16) unsigned short resb[16][168];
  __shared__ float ysh[80][37];
  __shared__ float aoutsh[80];
  __shared__ float asc[36], bsc[36], bets[36], alps[36], w2s[36];
  __shared__ float psum[80], psq[80];

  for (int e = tid; e < 80 * 36; e += 512) {
    ysh[e / 36][e % 36] = ws_y[(size_t)base * 180 + e];
  }
  if (tid < 36) {
    double s = 0.0, q = 0.0;
#pragma unroll
    for (int sh = 0; sh < NSHARD; sh++) {
      s += gstats[sh * SHARD_STRIDE + AU_SUM + tid];
      q += gstats[sh * SHARD_STRIDE + AU_SQ + tid];
    }
    const double m = s * (1.0 / ((double)NB * NK));
    const double var = q * (1.0 / ((double)NB * NK)) - m * m;
    const float rstd = (float)(1.0 / sqrt(var + 1e-8));
    const float g = au_gamma[tid] * rstd;
    asc[tid] = g; bsc[tid] = au_bbeta[tid] - (float)m * g;
    bets[tid] = au_beta[tid];
    alps[tid] = au_alpha[tid];
    w2s[tid] = au_W2[tid];
  }
  if (tid < 80) { psum[tid] = 0.f; psq[tid] = 0.f; }
  __syncthreads();

  const float bias2 = au_b2[0];
  if (tid < 80) {
    float acc = 0.f;
#pragma unroll
    for (int j = 0; j < 36; j++) {
      const float yv = ysh[tid][j];
      const float bn = yv * asc[j] + bsc[j];
      const float xn = sigm(bets[j] * bn);
      acc = fmaf(alps[j] * (1.f - xn) * yv + xn * yv, w2s[j], acc);
    }
    aoutsh[tid] = acc + bias2;
  }
  __syncthreads();

  for (int r = 0; r < 2; r++) {
    const int lm = r * 8 + wv;
    const int row = base + lm;
    const unsigned short icb = ws_ic[(size_t)row * 64 + lane];
    float fh0 = 0.f, fh1 = 0.f;
#pragma unroll
    for (int k = 0; k < NK; k++) {
      const float aok = aoutsh[lm * 5 + k];
      const unsigned short xwb = ws_xw[((size_t)row * NK + k) * 64 + lane];
      fh0 = fmaf(bf2f(xwb), aok, fh0);
      if (lane < 32) {
        const int rvk = ws_hr[row * NK + k];
        fh1 = fmaf(rate_tab[rvk * NH + lane], aok, fh1);
      }
    }
    resb[lm][lane] = icb;
    resb[lm][64 + lane] = f2bf(fh0);
    if (lane < 32) resb[lm][128 + lane] = f2bf(fh1);
  }
  __syncthreads();

  // GEMM M=16 (1 tile) x N=80 (5 nt), K=160 (5 steps); waves 0-4
  const int l15 = lane & 15, lhi = lane >> 4;
  if (wv < 5) {
    const int nt = wv;
    f32x4 acc = {0.f, 0.f, 0.f, 0.f};
#pragma unroll
    for (int ks = 0; ks < 5; ks++) {
      const int k0 = ks * 32 + lhi * 8;
      const bf16x8 a = *reinterpret_cast<const bf16x8*>(&resb[l15][k0]);
      const bf16x8 b = *reinterpret_cast<const bf16x8*>(
          &ws_l1t[(size_t)(nt * 16 + l15) * 168 + k0]);
      acc = __builtin_amdgcn_mfma_f32_16x16x32_bf16(a, b, acc, 0, 0, 0);
    }
    const int n = nt * 16 + l15;
    const float bn = l1_b[n];
    float ls = 0.f, lq = 0.f;
#pragma unroll
    for (int reg = 0; reg < 4; reg++) {
      const int m = 4 * lhi + reg;
      const float h = acc[reg] + bn;
      ws_h1[(size_t)(base + m) * 80 + n] = h;
      ls += h; lq += h * h;
    }
    atomicAdd(&psum[n], ls);
    atomicAdd(&psq[n], lq);
  }
  __syncthreads();
  if (tid < 80) {
    atomicAdd(&gstats[shard * SHARD_STRIDE + D1_SUM + tid], (double)psum[tid]);
    atomicAdd(&gstats[shard * SHARD_STRIDE + D1_SQ + tid], (double)psq[tid]);
  }
}

// ---- Kernel 5: dice2(h1), h @ l2_W via MFMA, d2 stats (16 rows/block) -------
__global__ __launch_bounds__(512) void k5(
    const float* __restrict__ d1_alpha, const float* __restrict__ d1_beta,
    const float* __restrict__ d1_gamma, const float* __restrict__ d1_bbeta,
    const unsigned short* __restrict__ ws_l2t, const float* __restrict__ l2_b,
    const float* __restrict__ ws_h1,
    double* __restrict__ gstats,
    float* __restrict__ ws_h2)
{
  const int tid = threadIdx.x, lane = tid & 63, wv = tid >> 6;
  const int shard = blockIdx.x & (NSHARD - 1);
  __shared__ alignas(16) unsigned short h1b[16][104];
  __shared__ float a1[80], c1[80];
  __shared__ float psum[40], psq[40];

  if (tid < 80) {
    double s = 0.0, q = 0.0;
#pragma unroll
    for (int sh = 0; sh < NSHARD; sh++) {
      s += gstats[sh * SHARD_STRIDE + D1_SUM + tid];
      q += gstats[sh * SHARD_STRIDE + D1_SQ + tid];
    }
    const double m = s * (1.0 / (double)NB);
    const double var = q * (1.0 / (double)NB) - m * m;
    const float rstd = (float)(1.0 / sqrt(var + 1e-8));
    const float g = d1_gamma[tid] * rstd;
    a1[tid] = g; c1[tid] = d1_bbeta[tid] - (float)m * g;
  }
  if (tid < 40) { psum[tid] = 0.f; psq[tid] = 0.f; }
  __syncthreads();

  for (int r = 0; r < 2; r++) {
    const int lm = r * 8 + wv;
    const int row = blockIdx.x * 16 + lm;
    {
      const float v = ws_h1[(size_t)row * 80 + lane];
      const float bn = v * a1[lane] + c1[lane];
      const float xn = sigm(d1_beta[lane] * bn);
      h1b[lm][lane] = f2bf(d1_alpha[lane] * (1.f - xn) * v + xn * v);
    }
    const int o = 64 + lane;
    if (lane < 16) {
      const float v = ws_h1[(size_t)row * 80 + o];
      const float bn = v * a1[o] + c1[o];
      const float xn = sigm(d1_beta[o] * bn);
      h1b[lm][o] = f2bf(d1_alpha[o] * (1.f - xn) * v + xn * v);
    } else if (lane < 32) {
      h1b[lm][o] = 0;
    }
  }
  __syncthreads();

  // GEMM M=16 (1 tile) x N=48 (3 nt), K=96 (3 steps); waves 0-2
  const int l15 = lane & 15, lhi = lane >> 4;
  if (wv < 3) {
    const int nt = wv;
    f32x4 acc = {0.f, 0.f, 0.f, 0.f};
#pragma unroll
    for (int ks = 0; ks < 3; ks++) {
      const int k0 = ks * 32 + lhi * 8;
      const bf16x8 a = *reinterpret_cast<const bf16x8*>(&h1b[l15][k0]);
      const bf16x8 b = *reinterpret_cast<const bf16x8*>(
          &ws_l2t[(size_t)(nt * 16 + l15) * 104 + k0]);
      acc = __builtin_amdgcn_mfma_f32_16x16x32_bf16(a, b, acc, 0, 0, 0);
    }
    const int n = nt * 16 + l15;
    if (n < 40) {
      const float bn = l2_b[n];
      float ls = 0.f, lq = 0.f;
#pragma unroll
      for (int reg = 0; reg < 4; reg++) {
        const int m = 4 * lhi + reg;
        const float h = acc[reg] + bn;
        ws_h2[(size_t)(blockIdx.x * 16 + m) * 40 + n] = h;
        ls += h; lq += h * h;
      }
      atomicAdd(&psum[n], ls);
      atomicAdd(&psq[n], lq);
    }
  }
  __syncthreads();
  if (tid < 40) {
    atomicAdd(&gstats[shard * SHARD_STRIDE + D2_SUM + tid], (double)psum[tid]);
    atomicAdd(&gstats[shard * SHARD_STRIDE + D2_SQ + tid], (double)psq[tid]);
  }
}

// ---- Kernel 7: dice2(h2), logits, probs, loss (+ last-block finalize) -------
// 512 thr, 32 rows/block (grid 512).
__global__ __launch_bounds__(512) void k7(
    const int* __restrict__ lb,
    const float* __restrict__ d2_alpha, const float* __restrict__ d2_beta,
    const float* __restrict__ d2_gamma, const float* __restrict__ d2_bbeta,
    const float* __restrict__ l3_W, const float* __restrict__ l3_b,
    const float* __restrict__ ws_h2,
    double* __restrict__ gstats,
    float* __restrict__ out)
{
  const int tid = threadIdx.x, lane = tid & 63, wv = tid >> 6;
  __shared__ float a2[40], c2[40];
  __shared__ float wls[8];
  if (tid < 40) {
    double s = 0.0, q = 0.0;
#pragma unroll
    for (int sh = 0; sh < NSHARD; sh++) {
      s += gstats[sh * SHARD_STRIDE + D2_SUM + tid];
      q += gstats[sh * SHARD_STRIDE + D2_SQ + tid];
    }
    const double m = s * (1.0 / (double)NB);
    const double var = q * (1.0 / (double)NB) - m * m;
    const float rstd = (float)(1.0 / sqrt(var + 1e-8));
    const float g = d2_gamma[tid] * rstd;
    a2[tid] = g; c2[tid] = d2_bbeta[tid] - (float)m * g;
  }
  __syncthreads();

  float wj = 0, b2j = 0, c2j = 0, betaj = 0, alphaj = 0;
  if (lane < 40) {
    wj = l3_W[lane]; b2j = a2[lane]; c2j = c2[lane];
    betaj = d2_beta[lane]; alphaj = d2_alpha[lane];
  }
  const float b3 = l3_b[0];

  float lacc = 0.f;
  for (int r = 0; r < 4; r++) {
    const int row = blockIdx.x * 32 + r * 8 + wv;
    float p = 0.f;
    if (lane < 40) {
      const float v = ws_h2[(size_t)row * 40 + lane];
      const float bn = v * b2j + c2j;
      const float xn = sigm(betaj * bn);
      p = (alphaj * (1.f - xn) * v + xn * v) * wj;
    }
    const float logit = wsum64(p) + b3;
    if (lane == 0) {
      out[row] = 1.f / (1.f + expf(-logit));
      const float lab = (float)lb[row];
      lacc += fmaxf(logit, 0.f) - logit * lab + log1pf(expf(-fabsf(logit)));
    }
  }
  if (lane == 0) wls[wv] = lacc;
  __syncthreads();
  if (tid == 0) {
    double* g_loss = gstats + LOSS_OFF;
    unsigned int* g_cnt = (unsigned int*)(gstats + CNT_OFF);
    float s = 0.f;
#pragma unroll
    for (int w = 0; w < 8; w++) s += wls[w];
    atomicAdd(g_loss, (double)s);
    __threadfence();
    const unsigned prev = atomicAdd(g_cnt, 1u);
    if (prev == (unsigned)(gridDim.x - 1)) {
      const double tot = atomicAdd(g_loss, 0.0);
      out[NB] = (float)(tot * (1.0 / (double)NB));
    }
  }
}

} // namespace

extern "C" void kernel_launch(void* const* d_in, const int* in_sizes, int n_in,
                              void* d_out, int out_size, void* d_ws, size_t ws_size,
                              hipStream_t stream) {
  const int* iid       = (const int*)d_in[0];
  const int* aid       = (const int*)d_in[1];
  const int* lb        = (const int*)d_in[2];
  const int* hist_iid  = (const int*)d_in[3];
  const int* hist_aid  = (const int*)d_in[4];
  const int* hist_rate = (const int*)d_in[5];
  const float* item_tab = (const float*)d_in[6];
  const float* cate_tab = (const float*)d_in[7];
  const float* rate_tab = (const float*)d_in[8];
  const float* au_W1    = (const float*)d_in[9];
  const float* au_b1    = (const float*)d_in[10];
  const float* au_alpha = (const float*)d_in[11];
  const float* au_beta  = (const float*)d_in[12];
  const float* au_gamma = (const float*)d_in[13];
  const float* au_bbeta = (const float*)d_in[14];
  const float* au_W2    = (const float*)d_in[15];
  const float* au_b2    = (const float*)d_in[16];
  const float* l1_W     = (const float*)d_in[17];
  const float* l1_b     = (const float*)d_in[18];
  const float* d1_alpha = (const float*)d_in[19];
  const float* d1_beta  = (const float*)d_in[20];
  const float* d1_gamma = (const float*)d_in[21];
  const float* d1_bbeta = (const float*)d_in[22];
  const float* l2_W     = (const float*)d_in[23];
  const float* l2_b     = (const float*)d_in[24];
  const float* d2_alpha = (const float*)d_in[25];
  const float* d2_beta  = (const float*)d_in[26];
  const float* d2_gamma = (const float*)d_in[27];
  const float* d2_bbeta = (const float*)d_in[28];
  const float* l3_W     = (const float*)d_in[29];
  const float* l3_b     = (const float*)d_in[30];
  float* out = (float*)d_out;

  double* gstats = (double*)d_ws;
  float* fbase  = (float*)((char*)d_ws + 32768);
  float* ws_y   = fbase;                                  // NB*180 f32
  float* ws_h1  = fbase + (size_t)NB * 180;               // NB*80 f32
  float* ws_h2  = ws_h1 + (size_t)NB * 80;                // NB*40 f32
  int*   ws_hr  = (int*)(ws_h2 + (size_t)NB * 40);        // NB*5 int
  unsigned short* ws_xw = (unsigned short*)(ws_hr + (size_t)NB * NK); // NB*5*64 bf16
  unsigned short* ws_ic = ws_xw + (size_t)NB * NK * 64;   // NB*64 bf16
  unsigned short* ws_l1t = ws_ic + (size_t)NB * 64;       // 80*168 bf16
  unsigned short* ws_l2t = ws_l1t + 80 * 168;             // 48*104 bf16

  hipMemsetAsync(d_ws, 0, (CNT_OFF + 2) * sizeof(double), stream);
  k1<<<dim3(NB / 16), 512, 0, stream>>>(iid, aid, hist_iid, hist_aid, hist_rate,
                              item_tab, cate_tab, au_W1, au_b1, l1_W, l2_W,
                              ws_y, ws_xw, ws_ic, ws_hr, ws_l1t, ws_l2t, gstats);
  k3<<<dim3(NB / 16), 512, 0, stream>>>(rate_tab,
                              au_alpha, au_beta, au_gamma, au_bbeta, au_W2, au_b2,
                              ws_l1t, l1_b, ws_y, ws_xw, ws_ic, ws_hr,
                              gstats, ws_h1);
  k5<<<dim3(NB / 16), 512, 0, stream>>>(d1_alpha, d1_beta, d1_gamma, d1_bbeta,
                              ws_l2t, l2_b, ws_h1, gstats, ws_h2);
  k7<<<dim3(NB / 32), 512, 0, stream>>>(lb, d2_alpha, d2_beta, d2_gamma, d2_bbeta, l3_W, l3_b,
                              ws_h2, gstats, out);
}